// Round 1
// baseline (3537.363 us; speedup 1.0000x reference)
//
#include <hip/hip_runtime.h>
#include <math.h>

#define PLANE 16384   // 128*128
#define NPLANES 512   // B(128) * C(4)

// ---------------- FWHT (2D, in LDS) ----------------
__device__ __forceinline__ void fwht2d(float* a, int tid) {
    // along w (within each row)
#pragma unroll
    for (int d = 1; d < 128; d <<= 1) {
        __syncthreads();
        for (int k = 0; k < 32; ++k) {
            int p = tid + (k << 8);
            int row = p >> 6;
            int j = p & 63;
            int lo = ((j & ~(d - 1)) << 1) | (j & (d - 1));
            int i0 = (row << 7) + lo;
            float u = a[i0], v = a[i0 + d];
            a[i0] = u + v;
            a[i0 + d] = u - v;
        }
    }
    // along h (within each column)
#pragma unroll
    for (int d = 1; d < 128; d <<= 1) {
        __syncthreads();
        for (int k = 0; k < 32; ++k) {
            int p = tid + (k << 8);
            int w = p & 127;
            int j = p >> 7;
            int lo = ((j & ~(d - 1)) << 1) | (j & (d - 1));
            int i0 = (lo << 7) + w;
            float u = a[i0], v = a[i0 + (d << 7)];
            a[i0] = u + v;
            a[i0 + (d << 7)] = u - v;
        }
    }
    __syncthreads();
}

// FWHT2 -> *v -> hard-thresh (store optional, KL accumulate) -> (+add optional)
// -> FWHT2 -> /16384 -> crop(122x122, zero pad) store
__global__ __launch_bounds__(256) void fwht_kernel(
    const float* __restrict__ in, const float* __restrict__ vmat,
    const float* __restrict__ tmat, const float* __restrict__ addbuf,
    float* __restrict__ outThresh, float* __restrict__ outInv,
    float* __restrict__ klbins)
{
    __shared__ float a[PLANE];
    int plane = blockIdx.x;
    int tid = threadIdx.x;
    const float* src = in + (size_t)plane * PLANE;
    for (int i = tid; i < PLANE; i += 256) a[i] = src[i];
    fwht2d(a, tid);
    float local = 0.f;
    float* dstT = outThresh ? outThresh + (size_t)plane * PLANE : nullptr;
    const float* addp = addbuf ? addbuf + (size_t)plane * PLANE : nullptr;
    for (int i = tid; i < PLANE; i += 256) {
        float y = a[i] * vmat[i];
        float t = fabsf(tmat[i]);
        y = (fabsf(y) > t) ? y : 0.f;
        local += 1.f / (1.f + __expf(-fabsf(y)));   // sigmoid(|y|)
        if (dstT) dstT[i] = y;
        if (addp) y += addp[i];
        a[i] = y;
    }
    atomicAdd(&klbins[tid & 63], local);  // i%64 == tid%64 for stride-256 loop
    fwht2d(a, tid);
    float* dst = outInv + (size_t)plane * PLANE;
    const float s = 1.f / 16384.f;
    for (int i = tid; i < PLANE; i += 256) {
        int h = i >> 7, w = i & 127;
        dst[i] = (h < 122 && w < 122) ? a[i] * s : 0.f;
    }
}

// ---------------- conv1: 1->4, k16, s2, p1 : x[B,1,256,256] -> [B,4,128,128] padded ----------------
__global__ __launch_bounds__(256) void conv1_kernel(
    const float* __restrict__ x, const float* __restrict__ w1,
    const float* __restrict__ b1, float* __restrict__ out)
{
    __shared__ float tile[78 * 79];
    __shared__ float wsm[1024];
    int tx = blockIdx.x, ty = blockIdx.y, b = blockIdx.z;
    int tid = threadIdx.x;
    for (int i = tid; i < 1024; i += 256) wsm[i] = w1[i];
    const float* xp = x + (size_t)b * 65536;
    int bi = ty * 64 - 1, bj = tx * 64 - 1;
    for (int i = tid; i < 78 * 78; i += 256) {
        int r = i / 78, c = i - r * 78;
        int gi = bi + r, gj = bj + c;
        float v = 0.f;
        if (gi >= 0 && gi < 256 && gj >= 0 && gj < 256) v = xp[gi * 256 + gj];
        tile[r * 79 + c] = v;
    }
    __syncthreads();
    int lx = tid & 31, ly0 = tid >> 5;
    float acc[4][4];
#pragma unroll
    for (int r = 0; r < 4; ++r)
#pragma unroll
        for (int c = 0; c < 4; ++c) acc[r][c] = 0.f;
    for (int kh = 0; kh < 16; ++kh) {
#pragma unroll 4
        for (int kw = 0; kw < 16; ++kw) {
            float w0 = wsm[kh * 16 + kw];
            float w1v = wsm[256 + kh * 16 + kw];
            float w2v = wsm[512 + kh * 16 + kw];
            float w3v = wsm[768 + kh * 16 + kw];
#pragma unroll
            for (int r = 0; r < 4; ++r) {
                int ly = ly0 + r * 8;
                float iv = tile[(2 * ly + kh) * 79 + 2 * lx + kw];
                acc[r][0] += iv * w0;
                acc[r][1] += iv * w1v;
                acc[r][2] += iv * w2v;
                acc[r][3] += iv * w3v;
            }
        }
    }
#pragma unroll
    for (int r = 0; r < 4; ++r) {
        int oh = ty * 32 + ly0 + r * 8;
        int ow = tx * 32 + lx;
        bool valid = (oh < 122) && (ow < 122);
#pragma unroll
        for (int c = 0; c < 4; ++c) {
            size_t o = (((size_t)b * 4 + c) << 14) + (oh << 7) + ow;
            out[o] = valid ? (acc[r][c] + b1[c]) : 0.f;
        }
    }
}

// ---------------- 7x7 conv, 4->4, pad 3 (optionally transposed weights + skip add) ----------------
__global__ __launch_bounds__(256) void conv7_kernel(
    const float* __restrict__ in, const float* __restrict__ w,
    const float* __restrict__ bias, const float* __restrict__ skip,
    float* __restrict__ out, int transposedW)
{
    __shared__ float tile[4][22][23];
    __shared__ float wsm[4][4][49];
    int tx = blockIdx.x, ty = blockIdx.y, b = blockIdx.z;
    int tid = threadIdx.x;
    for (int i = tid; i < 784; i += 256) {
        int oc = i / 196;
        int rem = i - oc * 196;
        int ic = rem / 49;
        int k = rem - ic * 49;
        float wv;
        if (!transposedW) {
            wv = w[(oc * 4 + ic) * 49 + k];
        } else {
            int kh = k / 7, kw = k - kh * 7;
            wv = w[(ic * 4 + oc) * 49 + (6 - kh) * 7 + (6 - kw)];
        }
        wsm[oc][ic][k] = wv;
    }
    int bi = ty * 16 - 3, bj = tx * 16 - 3;
    for (int i = tid; i < 4 * 22 * 22; i += 256) {
        int ic = i / 484;
        int rem = i - ic * 484;
        int r = rem / 22, c = rem - r * 22;
        int gi = bi + r, gj = bj + c;
        float v = 0.f;
        if (gi >= 0 && gi < 128 && gj >= 0 && gj < 128)
            v = in[(((size_t)b * 4 + ic) << 14) + (gi << 7) + gj];
        tile[ic][r][c] = v;
    }
    __syncthreads();
    int lx = tid & 15, ly = tid >> 4;
    float acc[4] = {0.f, 0.f, 0.f, 0.f};
#pragma unroll
    for (int ic = 0; ic < 4; ++ic) {
#pragma unroll
        for (int kh = 0; kh < 7; ++kh) {
#pragma unroll
            for (int kw = 0; kw < 7; ++kw) {
                float iv = tile[ic][ly + kh][lx + kw];
                int k = kh * 7 + kw;
                acc[0] += iv * wsm[0][ic][k];
                acc[1] += iv * wsm[1][ic][k];
                acc[2] += iv * wsm[2][ic][k];
                acc[3] += iv * wsm[3][ic][k];
            }
        }
    }
    int oh = ty * 16 + ly, ow = tx * 16 + lx;
    bool valid = (oh < 122) && (ow < 122);
#pragma unroll
    for (int oc = 0; oc < 4; ++oc) {
        size_t o = (((size_t)b * 4 + oc) << 14) + (oh << 7) + ow;
        float v = 0.f;
        if (valid) {
            v = acc[oc] + bias[oc];
            if (skip) v += skip[o];
        }
        out[o] = v;
    }
}

// ---------------- convT4: 4->1, k16, s2, p1, then * x : -> out[B,1,256,256] ----------------
__global__ __launch_bounds__(256) void convt4_kernel(
    const float* __restrict__ in, const float* __restrict__ w,
    const float* __restrict__ bias, const float* __restrict__ xin,
    float* __restrict__ out)
{
    __shared__ float tile[4][24][25];
    __shared__ float wsm[1024];
    int tx = blockIdx.x, ty = blockIdx.y, b = blockIdx.z;
    int tid = threadIdx.x;
    for (int i = tid; i < 1024; i += 256) wsm[i] = w[i];
    int bi = ty * 16 - 7, bj = tx * 16 - 7;
    for (int i = tid; i < 4 * 24 * 24; i += 256) {
        int ic = i / 576;
        int rem = i - ic * 576;
        int r = rem / 24, c = rem - r * 24;
        int gi = bi + r, gj = bj + c;
        float v = 0.f;
        if (gi >= 0 && gi < 128 && gj >= 0 && gj < 128)
            v = in[(((size_t)b * 4 + ic) << 14) + (gi << 7) + gj];
        tile[ic][r][c] = v;
    }
    __syncthreads();
    int lx = tid & 31, ly0 = tid >> 5;
    float bv = bias[0];
    int kw0 = (lx + 1) & 1;
    int iwb = ((lx + 1) >> 1) + 7;
#pragma unroll
    for (int r = 0; r < 4; ++r) {
        int ly = ly0 + r * 8;
        int oh = ty * 32 + ly, ow = tx * 32 + lx;
        int kh0 = (ly + 1) & 1;
        int ihb = ((ly + 1) >> 1) + 7;
        float acc = 0.f;
#pragma unroll
        for (int ic = 0; ic < 4; ++ic) {
#pragma unroll
            for (int i = 0; i < 8; ++i) {
                int kh = kh0 + 2 * i;
                const float* trow = &tile[ic][ihb - i][0];
                const float* wrow = &wsm[ic * 256 + kh * 16 + kw0];
#pragma unroll
                for (int j = 0; j < 8; ++j) {
                    acc += trow[iwb - j] * wrow[2 * j];
                }
            }
        }
        size_t o = (size_t)b * 65536 + (oh << 8) + ow;
        out[o] = (acc + bv) * xin[o];
    }
}

// ---------------- TV loss ----------------
__global__ __launch_bounds__(256) void tv_kernel(
    const float* __restrict__ out, float* __restrict__ acc)
{
    __shared__ float red[256];
    int tid = threadIdx.x;
    float local = 0.f;
    const int total = 128 * 65536;
    for (int idx = blockIdx.x * 256 + tid; idx < total; idx += gridDim.x * 256) {
        float v = out[idx];
        int hw = idx & 65535;
        if (hw < 65280) local += fabsf(out[idx + 256] - v);      // h < 255
        if ((idx & 255) != 255) local += fabsf(out[idx + 1] - v); // w < 255
    }
    red[tid] = local;
    __syncthreads();
    for (int s = 128; s > 0; s >>= 1) {
        if (tid < s) red[tid] += red[tid + s];
        __syncthreads();
    }
    if (tid == 0) atomicAdd(acc, red[0]);
}

// ---------------- init / finalize ----------------
__global__ void init_kernel(float* accum) {
    accum[threadIdx.x] = 0.f;
}

__global__ void finalize_kernel(const float* __restrict__ accum, float* __restrict__ lossout) {
    int t = threadIdx.x; // 64 threads = 1 wave
    float p = 1.f / (1.f + __expf(-0.001f));
    float term = 0.f;
    for (int s = 0; s < 3; ++s) {
        float qm = accum[s * 64 + t] * (1.f / 131072.f);
        term += p * logf(p / qm) + (1.f - p) * logf((1.f - p) / (1.f - qm));
    }
    for (int off = 32; off > 0; off >>= 1) term += __shfl_down(term, off);
    if (t == 0) {
        float tv = accum[192];
        lossout[0] = 0.05f * tv / 8388608.f + 0.1f * term;
    }
}

extern "C" void kernel_launch(void* const* d_in, const int* in_sizes, int n_in,
                              void* d_out, int out_size, void* d_ws, size_t ws_size,
                              hipStream_t stream) {
    (void)in_sizes; (void)n_in; (void)out_size; (void)ws_size;
    const float* x  = (const float*)d_in[0];
    const float* v1 = (const float*)d_in[2];
    const float* T1 = (const float*)d_in[3];
    const float* v2 = (const float*)d_in[4];
    const float* T2 = (const float*)d_in[5];
    const float* v3 = (const float*)d_in[6];
    const float* T3 = (const float*)d_in[7];
    const float* w1 = (const float*)d_in[8];
    const float* b1 = (const float*)d_in[9];
    const float* w2 = (const float*)d_in[10];
    const float* b2 = (const float*)d_in[11];
    const float* w3 = (const float*)d_in[12];
    const float* b3 = (const float*)d_in[13];
    const float* w4 = (const float*)d_in[14];
    const float* b4 = (const float*)d_in[15];
    float* out = (float*)d_out;

    float* W0 = (float*)d_ws;                 // plane buffer 0 [512*16384]
    float* W1 = W0 + (size_t)NPLANES * PLANE; // plane buffer 1 (x6)
    float* W2 = W1 + (size_t)NPLANES * PLANE; // plane buffer 2
    float* accum = W2 + (size_t)NPLANES * PLANE; // [0:64) kl1 [64:128) kl2 [128:192) kl3 [192] tv
    float* x10buf = out; // reuse d_out's 8388608-float region as x10 scratch

    init_kernel<<<1, 256, 0, stream>>>(accum);
    // x1 (padded) -> W0
    conv1_kernel<<<dim3(4, 4, 128), 256, 0, stream>>>(x, w1, b1, W0);
    // x6 -> W1, x9 -> W2, KL1
    fwht_kernel<<<NPLANES, 256, 0, stream>>>(W0, v1, T1, nullptr, W1, W2, accum + 0);
    // x10 -> d_out scratch
    conv7_kernel<<<dim3(8, 8, 128), 256, 0, stream>>>(W2, w2, b2, nullptr, x10buf, 0);
    // x15 (not stored), KL2, x18 -> W0
    fwht_kernel<<<NPLANES, 256, 0, stream>>>(x10buf, v2, T2, nullptr, nullptr, W0, accum + 64);
    // x19 = convT3(x18) + x10 -> W2
    conv7_kernel<<<dim3(8, 8, 128), 256, 0, stream>>>(W0, w3, b3, x10buf, W2, 1);
    // x24 (not stored), KL3, +x6, x27 -> W0
    fwht_kernel<<<NPLANES, 256, 0, stream>>>(W2, v3, T3, W1, nullptr, W0, accum + 128);
    // out = convT4(x27) * x  -> d_out (overwrites x10 scratch, already consumed)
    convt4_kernel<<<dim3(8, 8, 128), 256, 0, stream>>>(W0, w4, b4, x, out);
    // TV on out
    tv_kernel<<<2048, 256, 0, stream>>>(out, accum + 192);
    // loss scalar
    finalize_kernel<<<1, 64, 0, stream>>>(accum, out + 8388608);
}

// Round 2
// 869.675 us; speedup vs baseline: 4.0675x; 4.0675x over previous
//
#include <hip/hip_runtime.h>
#include <math.h>

#define PLANE 16384   // 128*128
#define NPLANES 512   // B(128) * C(4)

// ---------------- FWHT (2D, in LDS) ----------------
__device__ __forceinline__ void fwht2d(float* a, int tid) {
#pragma unroll
    for (int d = 1; d < 128; d <<= 1) {
        __syncthreads();
        for (int k = 0; k < 32; ++k) {
            int p = tid + (k << 8);
            int row = p >> 6;
            int j = p & 63;
            int lo = ((j & ~(d - 1)) << 1) | (j & (d - 1));
            int i0 = (row << 7) + lo;
            float u = a[i0], v = a[i0 + d];
            a[i0] = u + v;
            a[i0 + d] = u - v;
        }
    }
#pragma unroll
    for (int d = 1; d < 128; d <<= 1) {
        __syncthreads();
        for (int k = 0; k < 32; ++k) {
            int p = tid + (k << 8);
            int w = p & 127;
            int j = p >> 7;
            int lo = ((j & ~(d - 1)) << 1) | (j & (d - 1));
            int i0 = (lo << 7) + w;
            float u = a[i0], v = a[i0 + (d << 7)];
            a[i0] = u + v;
            a[i0 + (d << 7)] = u - v;
        }
    }
    __syncthreads();
}

__global__ __launch_bounds__(256) void fwht_kernel(
    const float* __restrict__ in, const float* __restrict__ vmat,
    const float* __restrict__ tmat, const float* __restrict__ addbuf,
    float* __restrict__ outThresh, float* __restrict__ outInv,
    float* __restrict__ klbins)
{
    __shared__ float a[PLANE];
    int plane = blockIdx.x;
    int tid = threadIdx.x;
    const float4* src4 = (const float4*)(in + (size_t)plane * PLANE);
    float4* a4 = (float4*)a;
    for (int i = tid; i < PLANE / 4; i += 256) a4[i] = src4[i];
    fwht2d(a, tid);
    float local = 0.f;
    float* dstT = outThresh ? outThresh + (size_t)plane * PLANE : nullptr;
    const float* addp = addbuf ? addbuf + (size_t)plane * PLANE : nullptr;
    for (int i = tid; i < PLANE; i += 256) {
        float y = a[i] * vmat[i];
        float t = fabsf(tmat[i]);
        y = (fabsf(y) > t) ? y : 0.f;
        local += 1.f / (1.f + __expf(-fabsf(y)));   // sigmoid(|y|)
        if (dstT) dstT[i] = y;
        if (addp) y += addp[i];
        a[i] = y;
    }
    atomicAdd(&klbins[tid & 63], local);  // i%64 == tid%64 for stride-256 loop
    fwht2d(a, tid);
    float* dst = outInv + (size_t)plane * PLANE;
    const float s = 1.f / 16384.f;
    for (int i = tid; i < PLANE; i += 256) {
        int h = i >> 7, w = i & 127;
        dst[i] = (h < 122 && w < 122) ? a[i] * s : 0.f;
    }
}

// ---------------- weight prep: canonicalize w3 (transposed 7x7) and w4 (convT 16x16 s2) ----------------
__global__ void prep_weights(const float* __restrict__ w3, const float* __restrict__ w4,
                             float* __restrict__ w3c, float* __restrict__ w4p)
{
    int tid = blockIdx.x * 256 + threadIdx.x;
    if (tid < 784) {
        int oc = tid / 196;
        int rem = tid - oc * 196;
        int ic = rem / 49;
        int k = rem - ic * 49;
        int kh = k / 7, kw = k - kh * 7;
        w3c[(oc * 4 + ic) * 49 + k] = w3[(ic * 4 + oc) * 49 + (6 - kh) * 7 + (6 - kw)];
    }
    if (tid < 1024) {
        // layout [ic:2][pa:1][pb:1][t:3][u:3]
        int u = tid & 7, t = (tid >> 3) & 7, pb = (tid >> 6) & 1, pa = (tid >> 7) & 1, ic = tid >> 8;
        int kh = 2 * t + (pa ? 0 : 1);
        int kw = 2 * u + (pb ? 0 : 1);
        w4p[tid] = w4[ic * 256 + kh * 16 + kw];
    }
}

// ---------------- conv1: 1->4, k16, s2, p1 : x[B,1,256,256] -> [B,4,128,128] padded ----------------
__global__ __launch_bounds__(256) void conv1_kernel(
    const float* __restrict__ x, const float* __restrict__ w1,
    const float* __restrict__ b1, float* __restrict__ out)
{
    __shared__ float tile[78][80];
    int tx = blockIdx.x, ty = blockIdx.y, b = blockIdx.z;
    int tid = threadIdx.x;
    const float* xp = x + (size_t)b * 65536;
    int r0g = ty * 64 - 1, c0g = tx * 64 - 1;
    for (int i = tid; i < 78 * 78; i += 256) {
        int rr = i / 78, cc = i - rr * 78;
        int gi = r0g + rr, gj = c0g + cc;
        tile[rr][cc] = (gi >= 0 && gi < 256 && gj >= 0 && gj < 256) ? xp[gi * 256 + gj] : 0.f;
    }
    __syncthreads();
    int cg = tid & 7, r = tid >> 3;
    int B = cg * 4;
    float acc[4][4];
#pragma unroll
    for (int oc = 0; oc < 4; ++oc)
#pragma unroll
        for (int c = 0; c < 4; ++c) acc[oc][c] = 0.f;
#pragma unroll 1
    for (int kh = 0; kh < 16; ++kh) {
        float win[24];
        const float* trow = &tile[2 * r + kh][2 * B];
#pragma unroll
        for (int k = 0; k < 6; ++k)
            *(float4*)&win[4 * k] = *(const float4*)&trow[4 * k];
#pragma unroll
        for (int oc = 0; oc < 4; ++oc) {
            const float* wr = w1 + oc * 256 + kh * 16;
#pragma unroll
            for (int kw = 0; kw < 16; ++kw) {
                float wv = wr[kw];
#pragma unroll
                for (int c = 0; c < 4; ++c)
                    acc[oc][c] = fmaf(win[2 * c + kw], wv, acc[oc][c]);
            }
        }
    }
    int oh = ty * 32 + r;
    int owb = tx * 32 + B;
    bool rowv = oh < 122;
#pragma unroll
    for (int oc = 0; oc < 4; ++oc) {
        float bv = b1[oc];
        float4 res;
        res.x = (rowv && owb + 0 < 122) ? acc[oc][0] + bv : 0.f;
        res.y = (rowv && owb + 1 < 122) ? acc[oc][1] + bv : 0.f;
        res.z = (rowv && owb + 2 < 122) ? acc[oc][2] + bv : 0.f;
        res.w = (rowv && owb + 3 < 122) ? acc[oc][3] + bv : 0.f;
        *(float4*)&out[(((size_t)b * 4 + oc) << 14) + (oh << 7) + owb] = res;
    }
}

// ---------------- 7x7 conv, 4->4, pad 3, canonical weights [oc][ic][kh][kw], optional skip ----------------
__global__ __launch_bounds__(256) void conv7_kernel(
    const float* __restrict__ in, const float* __restrict__ w,
    const float* __restrict__ bias, const float* __restrict__ skip,
    float* __restrict__ out)
{
    __shared__ float tile[4][38][40];
    int tx = blockIdx.x, ty = blockIdx.y, b = blockIdx.z;
    int tid = threadIdx.x;
    int r0g = ty * 32 - 3, c0g = tx * 32 - 3;
    for (int i = tid; i < 4 * 38 * 38; i += 256) {
        int ic = i / 1444;
        int rem = i - ic * 1444;
        int rr = rem / 38, cc = rem - rr * 38;
        int gi = r0g + rr, gj = c0g + cc;
        float v = 0.f;
        if (gi >= 0 && gi < 128 && gj >= 0 && gj < 128)
            v = in[(((size_t)b * 4 + ic) << 14) + (gi << 7) + gj];
        tile[ic][rr][cc] = v;
    }
    __syncthreads();
    int cg = tid & 7, r = tid >> 3;
    int B = cg * 4;
    float acc[4][4];
#pragma unroll
    for (int oc = 0; oc < 4; ++oc)
#pragma unroll
        for (int c = 0; c < 4; ++c) acc[oc][c] = 0.f;
#pragma unroll 1
    for (int ic = 0; ic < 4; ++ic) {
#pragma unroll 1
        for (int kh = 0; kh < 7; ++kh) {
            float win[12];
            const float* trow = &tile[ic][r + kh][B];
#pragma unroll
            for (int k = 0; k < 3; ++k)
                *(float4*)&win[4 * k] = *(const float4*)&trow[4 * k];
#pragma unroll
            for (int oc = 0; oc < 4; ++oc) {
                const float* wr = w + (oc * 4 + ic) * 49 + kh * 7;
#pragma unroll
                for (int kw = 0; kw < 7; ++kw) {
                    float wv = wr[kw];
#pragma unroll
                    for (int c = 0; c < 4; ++c)
                        acc[oc][c] = fmaf(win[c + kw], wv, acc[oc][c]);
                }
            }
        }
    }
    int oh = ty * 32 + r;
    int owb = tx * 32 + B;
    bool rowv = oh < 122;
#pragma unroll
    for (int oc = 0; oc < 4; ++oc) {
        size_t o = (((size_t)b * 4 + oc) << 14) + (oh << 7) + owb;
        float4 sv = make_float4(0.f, 0.f, 0.f, 0.f);
        if (skip) sv = *(const float4*)&skip[o];
        float bv = bias[oc];
        float4 res;
        res.x = (rowv && owb + 0 < 122) ? acc[oc][0] + bv + sv.x : 0.f;
        res.y = (rowv && owb + 1 < 122) ? acc[oc][1] + bv + sv.y : 0.f;
        res.z = (rowv && owb + 2 < 122) ? acc[oc][2] + bv + sv.z : 0.f;
        res.w = (rowv && owb + 3 < 122) ? acc[oc][3] + bv + sv.w : 0.f;
        *(float4*)&out[o] = res;
    }
}

// ---------------- convT4: 4->1, k16, s2, p1, parity-decomposed; then * x ----------------
#define CT_HALF(T, ROW, PA)                                                    \
    _Pragma("unroll")                                                          \
    for (int pb = 0; pb < 2; ++pb) {                                           \
        const float* w8 = wp + (((ic * 2 + (PA)) * 2 + pb) * 8 + (T)) * 8;     \
        _Pragma("unroll")                                                      \
        for (int u = 0; u < 8; ++u) {                                          \
            float wv = w8[u];                                                  \
            _Pragma("unroll")                                                  \
            for (int c = 0; c < 4; ++c)                                        \
                acc[PA][pb][c] = fmaf(ROW[8 + c + pb - u], wv, acc[PA][pb][c]);\
        }                                                                      \
    }

__global__ __launch_bounds__(256) void convt4_kernel(
    const float* __restrict__ in, const float* __restrict__ wp,
    const float* __restrict__ bias, const float* __restrict__ xin,
    float* __restrict__ out)
{
    __shared__ float tile[4][40][44];
    int tx = blockIdx.x, ty = blockIdx.y, b = blockIdx.z;
    int tid = threadIdx.x;
    int A0 = ty * 32, B0 = tx * 32;
    int r0g = A0 - 7, c0g = B0 - 8;
    for (int i = tid; i < 4 * 40 * 44; i += 256) {
        int ic = i / 1760;
        int rem = i - ic * 1760;
        int rr = rem / 44, cc = rem - rr * 44;
        int gi = r0g + rr, gj = c0g + cc;
        float v = 0.f;
        if (gi >= 0 && gi < 128 && gj >= 0 && gj < 128)
            v = in[(((size_t)b * 4 + ic) << 14) + (gi << 7) + gj];
        tile[ic][rr][cc] = v;
    }
    __syncthreads();
    int cg = tid & 7, ra = tid >> 3;
    float acc[2][2][4];
#pragma unroll
    for (int pa = 0; pa < 2; ++pa)
#pragma unroll
        for (int pb = 0; pb < 2; ++pb)
#pragma unroll
            for (int c = 0; c < 4; ++c) acc[pa][pb][c] = 0.f;
#pragma unroll 1
    for (int ic = 0; ic < 4; ++ic) {
        float bufA[16], bufB[16];
#pragma unroll
        for (int k = 0; k < 4; ++k)
            *(float4*)&bufB[4 * k] = *(const float4*)&tile[ic][ra + 8][4 * cg + 4 * k];
#pragma unroll 1
        for (int t2 = 0; t2 < 8; t2 += 2) {
#pragma unroll
            for (int k = 0; k < 4; ++k)
                *(float4*)&bufA[4 * k] = *(const float4*)&tile[ic][ra + 7 - t2][4 * cg + 4 * k];
            CT_HALF(t2, bufA, 0)
            CT_HALF(t2, bufB, 1)
#pragma unroll
            for (int k = 0; k < 4; ++k)
                *(float4*)&bufB[4 * k] = *(const float4*)&tile[ic][ra + 6 - t2][4 * cg + 4 * k];
            CT_HALF(t2 + 1, bufB, 0)
            CT_HALF(t2 + 1, bufA, 1)
        }
    }
    int oh0 = 2 * (A0 + ra);
    int owb = 2 * (B0 + 4 * cg);
    float bv = bias[0];
#pragma unroll
    for (int pa = 0; pa < 2; ++pa) {
        size_t o = (size_t)b * 65536 + (size_t)(oh0 + pa) * 256 + owb;
        float4 x0 = *(const float4*)&xin[o];
        float4 x1 = *(const float4*)&xin[o + 4];
        float4 r0, r1;
        r0.x = (acc[pa][0][0] + bv) * x0.x;
        r0.y = (acc[pa][1][0] + bv) * x0.y;
        r0.z = (acc[pa][0][1] + bv) * x0.z;
        r0.w = (acc[pa][1][1] + bv) * x0.w;
        r1.x = (acc[pa][0][2] + bv) * x1.x;
        r1.y = (acc[pa][1][2] + bv) * x1.y;
        r1.z = (acc[pa][0][3] + bv) * x1.z;
        r1.w = (acc[pa][1][3] + bv) * x1.w;
        *(float4*)&out[o] = r0;
        *(float4*)&out[o + 4] = r1;
    }
}

// ---------------- TV loss ----------------
__global__ __launch_bounds__(256) void tv_kernel(
    const float* __restrict__ out, float* __restrict__ acc)
{
    __shared__ float red[256];
    int tid = threadIdx.x;
    float local = 0.f;
    const int total = 128 * 65536;
    for (int idx = blockIdx.x * 256 + tid; idx < total; idx += gridDim.x * 256) {
        float v = out[idx];
        int hw = idx & 65535;
        if (hw < 65280) local += fabsf(out[idx + 256] - v);
        if ((idx & 255) != 255) local += fabsf(out[idx + 1] - v);
    }
    red[tid] = local;
    __syncthreads();
    for (int s = 128; s > 0; s >>= 1) {
        if (tid < s) red[tid] += red[tid + s];
        __syncthreads();
    }
    if (tid == 0) atomicAdd(acc, red[0]);
}

// ---------------- init / finalize ----------------
__global__ void init_kernel(float* accum) {
    accum[threadIdx.x] = 0.f;
}

__global__ void finalize_kernel(const float* __restrict__ accum, float* __restrict__ lossout) {
    int t = threadIdx.x; // 64 threads = 1 wave
    float p = 1.f / (1.f + __expf(-0.001f));
    float term = 0.f;
    for (int s = 0; s < 3; ++s) {
        float qm = accum[s * 64 + t] * (1.f / 131072.f);
        term += p * logf(p / qm) + (1.f - p) * logf((1.f - p) / (1.f - qm));
    }
    for (int off = 32; off > 0; off >>= 1) term += __shfl_down(term, off);
    if (t == 0) {
        float tv = accum[192];
        lossout[0] = 0.05f * tv / 8388608.f + 0.1f * term;
    }
}

extern "C" void kernel_launch(void* const* d_in, const int* in_sizes, int n_in,
                              void* d_out, int out_size, void* d_ws, size_t ws_size,
                              hipStream_t stream) {
    (void)in_sizes; (void)n_in; (void)out_size; (void)ws_size;
    const float* x  = (const float*)d_in[0];
    const float* v1 = (const float*)d_in[2];
    const float* T1 = (const float*)d_in[3];
    const float* v2 = (const float*)d_in[4];
    const float* T2 = (const float*)d_in[5];
    const float* v3 = (const float*)d_in[6];
    const float* T3 = (const float*)d_in[7];
    const float* w1 = (const float*)d_in[8];
    const float* b1 = (const float*)d_in[9];
    const float* w2 = (const float*)d_in[10];
    const float* b2 = (const float*)d_in[11];
    const float* w3 = (const float*)d_in[12];
    const float* b3 = (const float*)d_in[13];
    const float* w4 = (const float*)d_in[14];
    const float* b4 = (const float*)d_in[15];
    float* out = (float*)d_out;

    float* W0 = (float*)d_ws;
    float* W1 = W0 + (size_t)NPLANES * PLANE;
    float* W2 = W1 + (size_t)NPLANES * PLANE;
    float* accum = W2 + (size_t)NPLANES * PLANE; // [0:64) kl1 [64:128) kl2 [128:192) kl3 [192] tv
    float* w3c = accum + 256;   // 784 floats
    float* w4p = w3c + 784;     // 1024 floats
    float* x10buf = out;        // reuse d_out region as x10 scratch

    init_kernel<<<1, 256, 0, stream>>>(accum);
    prep_weights<<<4, 256, 0, stream>>>(w3, w4, w3c, w4p);
    // x1 (padded) -> W0
    conv1_kernel<<<dim3(4, 4, 128), 256, 0, stream>>>(x, w1, b1, W0);
    // x6 -> W1, x9 -> W2, KL1
    fwht_kernel<<<NPLANES, 256, 0, stream>>>(W0, v1, T1, nullptr, W1, W2, accum + 0);
    // x10 -> d_out scratch
    conv7_kernel<<<dim3(4, 4, 128), 256, 0, stream>>>(W2, w2, b2, nullptr, x10buf);
    // x15 (not stored), KL2, x18 -> W0
    fwht_kernel<<<NPLANES, 256, 0, stream>>>(x10buf, v2, T2, nullptr, nullptr, W0, accum + 64);
    // x19 = convT3(x18) + x10 -> W2
    conv7_kernel<<<dim3(4, 4, 128), 256, 0, stream>>>(W0, w3c, b3, x10buf, W2);
    // x24 (not stored), KL3, +x6, x27 -> W0
    fwht_kernel<<<NPLANES, 256, 0, stream>>>(W2, v3, T3, W1, nullptr, W0, accum + 128);
    // out = convT4(x27) * x
    convt4_kernel<<<dim3(4, 4, 128), 256, 0, stream>>>(W0, w4p, b4, x, out);
    // TV on out
    tv_kernel<<<2048, 256, 0, stream>>>(out, accum + 192);
    // loss scalar
    finalize_kernel<<<1, 64, 0, stream>>>(accum, out + 8388608);
}